// Round 1
// baseline (265.652 us; speedup 1.0000x reference)
//
#include <hip/hip_runtime.h>

// ===== Problem constants =====
// x: [28,14,14,256] -> mean over 7 -> xm[4,196,256]; avgpool2x2 -> xs[4,49,256]
// LAE: qkv = xm @ qkv_w^T [784,768]; per-pixel 3x3 dilated attn (d=1,3) -> y[784,256];
//      lae_out = y @ lae_proj_w^T + b [784,256]
// GAE: q = xm @ lq_w^T [784,128]; kv = xs @ lkv_w^T [196,256];
//      per (b,head) 196x49 attn -> ga[784,128]; gae_out = ga @ lproj_w^T + b [784,128]
// cls: out[4,2] = concat(lae,gae) flat [4,75264] @ cls_w^T + cls_b

#define WS_XM    0           // 784*256   = 200704
#define WS_XS    200704      // 196*256   = 50176
#define WS_QKV   250880      // 784*768   = 602112
#define WS_Y     852992      // 784*256   = 200704
#define WS_LAE   1053696     // 784*256   = 200704
#define WS_QB    1254400     // 784*128   = 100352
#define WS_KVB   1354752     // 196*256   = 50176
#define WS_GA    1404928     // 784*128   = 100352
#define WS_GAE   1505280     // 784*128   = 100352
// total floats = 1605632 (~6.4 MB)

// ---------- kernel 1: group-mean + 2x2 avg pool ----------
// grid 196 = 4 b * 49 quads, block 256 (one thread per channel)
__global__ __launch_bounds__(256) void k_mean_pool(const float* __restrict__ x,
                                                   float* __restrict__ xm,
                                                   float* __restrict__ xs) {
  const int blk = blockIdx.x;
  const int b = blk / 49;
  const int q = blk % 49;
  const int ph2 = q / 7, pw2 = q % 7;
  const int c = threadIdx.x;
  float s4 = 0.f;
  #pragma unroll
  for (int dy = 0; dy < 2; ++dy) {
    #pragma unroll
    for (int dx = 0; dx < 2; ++dx) {
      const int p = (ph2 * 2 + dy) * 14 + (pw2 * 2 + dx);
      float s = 0.f;
      #pragma unroll
      for (int g = 0; g < 7; ++g)
        s += x[((b * 7 + g) * 196 + p) * 256 + c];
      s *= (1.f / 7.f);
      xm[(b * 196 + p) * 256 + c] = s;
      s4 += s;
    }
  }
  xs[(b * 49 + q) * 256 + c] = s4 * 0.25f;
}

// ---------- generic tiled GEMM: C = A @ W^T (+bias), optional second weight ----
// A[M,K] row-major, W1[N1,K], W2[N2,K]; C1[M,N1], C2[M,N2].
// tile 32 rows x 64 cols, 256 threads, per-thread 2 rows x 4 cols.
__global__ __launch_bounds__(256) void k_gemm(const float* __restrict__ A, int M, int K,
                                              const float* __restrict__ W1,
                                              const float* __restrict__ b1,
                                              float* __restrict__ C1, int N1,
                                              const float* __restrict__ W2,
                                              const float* __restrict__ b2,
                                              float* __restrict__ C2, int N2) {
  __shared__ float As[32][68];
  __shared__ float Bs[64][68];
  const int tid = threadIdx.x;
  const int tx = tid & 15;   // col lane: cols tx + 16j
  const int ty = tid >> 4;   // row lane: rows ty + 16i
  const int rowBase = blockIdx.y * 32;
  const int colBase = blockIdx.x * 64;
  const int N = N1 + N2;

  float acc[2][4] = {{0.f,0.f,0.f,0.f},{0.f,0.f,0.f,0.f}};

  for (int kc = 0; kc < K; kc += 64) {
    // stage A tile 32x64 (512 float4, 2/thread)
    #pragma unroll
    for (int i = 0; i < 2; ++i) {
      const int e = tid + i * 256;
      const int r = e >> 4, k4 = (e & 15) << 2;
      const int row = rowBase + r;
      float4 v = make_float4(0.f, 0.f, 0.f, 0.f);
      if (row < M) v = *(const float4*)(A + (size_t)row * K + kc + k4);
      *(float4*)(&As[r][k4]) = v;
    }
    // stage B tile 64x64 (1024 float4, 4/thread)
    #pragma unroll
    for (int i = 0; i < 4; ++i) {
      const int e = tid + i * 256;
      const int n = e >> 4, k4 = (e & 15) << 2;
      const int col = colBase + n;
      float4 v = make_float4(0.f, 0.f, 0.f, 0.f);
      if (col < N1) v = *(const float4*)(W1 + (size_t)col * K + kc + k4);
      else if (col < N) v = *(const float4*)(W2 + (size_t)(col - N1) * K + kc + k4);
      *(float4*)(&Bs[n][k4]) = v;
    }
    __syncthreads();
    #pragma unroll
    for (int k = 0; k < 64; k += 4) {
      const float4 a0 = *(const float4*)(&As[ty][k]);
      const float4 a1 = *(const float4*)(&As[ty + 16][k]);
      const float4 c0 = *(const float4*)(&Bs[tx][k]);
      const float4 c1 = *(const float4*)(&Bs[tx + 16][k]);
      const float4 c2 = *(const float4*)(&Bs[tx + 32][k]);
      const float4 c3 = *(const float4*)(&Bs[tx + 48][k]);
      acc[0][0] += a0.x*c0.x + a0.y*c0.y + a0.z*c0.z + a0.w*c0.w;
      acc[0][1] += a0.x*c1.x + a0.y*c1.y + a0.z*c1.z + a0.w*c1.w;
      acc[0][2] += a0.x*c2.x + a0.y*c2.y + a0.z*c2.z + a0.w*c2.w;
      acc[0][3] += a0.x*c3.x + a0.y*c3.y + a0.z*c3.z + a0.w*c3.w;
      acc[1][0] += a1.x*c0.x + a1.y*c0.y + a1.z*c0.z + a1.w*c0.w;
      acc[1][1] += a1.x*c1.x + a1.y*c1.y + a1.z*c1.z + a1.w*c1.w;
      acc[1][2] += a1.x*c2.x + a1.y*c2.y + a1.z*c2.z + a1.w*c2.w;
      acc[1][3] += a1.x*c3.x + a1.y*c3.y + a1.z*c3.z + a1.w*c3.w;
    }
    __syncthreads();
  }

  #pragma unroll
  for (int j = 0; j < 4; ++j) {
    const int col = colBase + tx + 16 * j;
    if (col >= N) continue;
    float* Cd; int stride, cc; const float* bias;
    if (col < N1) { Cd = C1; stride = N1; cc = col; bias = b1; }
    else          { Cd = C2; stride = N2; cc = col - N1; bias = b2; }
    const float bv = bias ? bias[cc] : 0.f;
    #pragma unroll
    for (int i = 0; i < 2; ++i) {
      const int row = rowBase + ty + 16 * i;
      if (row < M) Cd[(size_t)row * stride + cc] = acc[i][j] + bv;
    }
  }
}

// ---------- LAE per-pixel dilated 3x3 window attention ----------
// grid 784 (b*196+p), block 256: thread c -> branch i=c>>7 (dil 1|3), head n, ch.
__global__ __launch_bounds__(256) void k_lae_attn(const float* __restrict__ qkv,
                                                  float* __restrict__ y) {
  const int bp = blockIdx.x;
  const int b = bp / 196, p = bp % 196;
  const int ph = p / 14, pw = p % 14;
  const int c = threadIdx.x;
  const int d = (c < 128) ? 1 : 3;
  const float qv = qkv[(size_t)bp * 768 + c];
  float s[9];
  #pragma unroll
  for (int j = 0; j < 9; ++j) {
    const int nh = ph + (j / 3 - 1) * d;
    const int nw = pw + (j % 3 - 1) * d;
    float kval = 0.f;
    if ((unsigned)nh < 14u && (unsigned)nw < 14u)
      kval = qkv[((size_t)(b * 196 + nh * 14 + nw)) * 768 + 256 + c];
    float t = qv * kval;
    t += __shfl_xor(t, 1);
    t += __shfl_xor(t, 2);
    t += __shfl_xor(t, 4);
    t += __shfl_xor(t, 8);
    t += __shfl_xor(t, 16);      // sum over the 32-channel group
    s[j] = t * 0.17677669529663687f;   // 32^-0.5
  }
  float mx = s[0];
  #pragma unroll
  for (int j = 1; j < 9; ++j) mx = fmaxf(mx, s[j]);
  float sum = 0.f;
  #pragma unroll
  for (int j = 0; j < 9; ++j) { s[j] = __expf(s[j] - mx); sum += s[j]; }
  const float inv = 1.f / sum;
  float out = 0.f;
  #pragma unroll
  for (int j = 0; j < 9; ++j) {
    const int nh = ph + (j / 3 - 1) * d;
    const int nw = pw + (j % 3 - 1) * d;
    if ((unsigned)nh < 14u && (unsigned)nw < 14u)
      out += s[j] * qkv[((size_t)(b * 196 + nh * 14 + nw)) * 768 + 512 + c];
  }
  y[(size_t)bp * 256 + c] = out * inv;
}

// ---------- GAE attention: 196 queries x 49 keys per (b,head) ----------
// grid 16 (b*4+h), block 256 (threads 0..195 = queries; all stage K/V).
__global__ __launch_bounds__(256) void k_gae_attn(const float* __restrict__ qb,
                                                  const float* __restrict__ kvb,
                                                  float* __restrict__ ga) {
  const int b = blockIdx.x >> 2, h = blockIdx.x & 3;
  __shared__ float Ks[49][32];
  __shared__ float Vs[49][32];
  const int tid = threadIdx.x;
  for (int e = tid; e < 49 * 32; e += 256) {
    const int kk = e >> 5, cc = e & 31;
    Ks[kk][cc] = kvb[(size_t)(b * 49 + kk) * 256 + h * 32 + cc];
    Vs[kk][cc] = kvb[(size_t)(b * 49 + kk) * 256 + 128 + h * 32 + cc];
  }
  __syncthreads();
  if (tid < 196) {
    float q[32], o[32];
    #pragma unroll
    for (int cc = 0; cc < 32; ++cc) {
      q[cc] = qb[(size_t)(b * 196 + tid) * 128 + h * 32 + cc];
      o[cc] = 0.f;
    }
    float m = -1e30f, l = 0.f;
    for (int kk = 0; kk < 49; ++kk) {
      float sc = 0.f;
      #pragma unroll
      for (int cc = 0; cc < 32; ++cc) sc += q[cc] * Ks[kk][cc];
      sc *= 0.177f;                  // SCALE_GAE (hard-coded in reference)
      if (sc > m) {
        const float r = __expf(m - sc);
        l *= r;
        #pragma unroll
        for (int cc = 0; cc < 32; ++cc) o[cc] *= r;
        m = sc;
      }
      const float pch = __expf(sc - m);
      l += pch;
      #pragma unroll
      for (int cc = 0; cc < 32; ++cc) o[cc] += pch * Vs[kk][cc];
    }
    const float inv = 1.f / l;
    #pragma unroll
    for (int cc = 0; cc < 32; ++cc)
      ga[(size_t)(b * 196 + tid) * 128 + h * 32 + cc] = o[cc] * inv;
  }
}

// ---------- classifier: out[b,cls] = dot(feat[b,:], cls_w[cls,:]) + cls_b ----
__global__ __launch_bounds__(256) void k_cls(const float* __restrict__ lae,
                                             const float* __restrict__ gae,
                                             const float* __restrict__ cw,
                                             const float* __restrict__ cb,
                                             float* __restrict__ out) {
  const int b = blockIdx.x >> 1, cls = blockIdx.x & 1;
  const int tid = threadIdx.x;
  float s = 0.f;
  for (int idx = tid; idx < 75264; idx += 256) {
    const int p = idx / 384, cc = idx % 384;
    const float f = (cc < 256) ? lae[(size_t)(b * 196 + p) * 256 + cc]
                               : gae[(size_t)(b * 196 + p) * 128 + (cc - 256)];
    s += f * cw[(size_t)cls * 75264 + idx];
  }
  __shared__ float red[256];
  red[tid] = s;
  __syncthreads();
  for (int st = 128; st > 0; st >>= 1) {
    if (tid < st) red[tid] += red[tid + st];
    __syncthreads();
  }
  if (tid == 0) out[b * 2 + cls] = red[0] + cb[cls];
}

extern "C" void kernel_launch(void* const* d_in, const int* in_sizes, int n_in,
                              void* d_out, int out_size, void* d_ws, size_t ws_size,
                              hipStream_t stream) {
  (void)in_sizes; (void)n_in; (void)out_size; (void)ws_size;
  const float* x          = (const float*)d_in[0];
  const float* qkv_w      = (const float*)d_in[1];
  const float* lae_proj_w = (const float*)d_in[2];
  const float* lae_proj_b = (const float*)d_in[3];
  const float* lq_w       = (const float*)d_in[4];
  const float* lkv_w      = (const float*)d_in[5];
  const float* lproj_w    = (const float*)d_in[6];
  const float* lproj_b    = (const float*)d_in[7];
  const float* cls_w      = (const float*)d_in[8];
  const float* cls_b      = (const float*)d_in[9];
  float* out = (float*)d_out;
  float* ws  = (float*)d_ws;

  float* xm   = ws + WS_XM;
  float* xs   = ws + WS_XS;
  float* qkvb = ws + WS_QKV;
  float* y    = ws + WS_Y;
  float* laeo = ws + WS_LAE;
  float* qb   = ws + WS_QB;
  float* kvb  = ws + WS_KVB;
  float* ga   = ws + WS_GA;
  float* gaeo = ws + WS_GAE;

  // 1) group mean + avg-pool
  k_mean_pool<<<196, 256, 0, stream>>>(x, xm, xs);
  // 2) fused qkv (N=768) + GAE q (N=128) projection from xm: N=896
  k_gemm<<<dim3(14, 25), 256, 0, stream>>>(xm, 784, 256,
                                           qkv_w, nullptr, qkvb, 768,
                                           lq_w, nullptr, qb, 128);
  // 3) GAE kv projection from xs
  k_gemm<<<dim3(4, 7), 256, 0, stream>>>(xs, 196, 256,
                                         lkv_w, nullptr, kvb, 256,
                                         nullptr, nullptr, nullptr, 0);
  // 4) LAE dilated window attention
  k_lae_attn<<<784, 256, 0, stream>>>(qkvb, y);
  // 5) GAE attention
  k_gae_attn<<<16, 256, 0, stream>>>(qb, kvb, ga);
  // 6) LAE output projection
  k_gemm<<<dim3(4, 25), 256, 0, stream>>>(y, 784, 256,
                                          lae_proj_w, lae_proj_b, laeo, 256,
                                          nullptr, nullptr, nullptr, 0);
  // 7) GAE output projection (K=128)
  k_gemm<<<dim3(2, 25), 256, 0, stream>>>(ga, 784, 128,
                                          lproj_w, lproj_b, gaeo, 128,
                                          nullptr, nullptr, nullptr, 0);
  // 8) classifier
  k_cls<<<8, 256, 0, stream>>>(laeo, gaeo, cls_w, cls_b, out);
}

// Round 2
// 130.802 us; speedup vs baseline: 2.0309x; 2.0309x over previous
//
#include <hip/hip_runtime.h>

// ===== Problem constants =====
// x: [28,14,14,256] -> mean over 7 -> xm[4,196,256]; avgpool2x2 -> xs[4,49,256]
// LAE: qkv = xm @ qkv_w^T [784,768]; per-pixel 3x3 dilated attn (d=1,3) -> y[784,256]
// GAE: q = xm @ lq_w^T [784,128]; kv = xs @ lkv_w^T [196,256]; attn -> ga[784,128]
// proj+cls fused: out[b,cls] = sum_p ( (y@Wl^T+bl)|p ⋅ cwl + (ga@Wg^T+bg)|p ⋅ cwg ) + cls_b

#define WS_XM    0           // 784*256  = 200704
#define WS_XS    200704      // 196*256  = 50176
#define WS_QKV   250880      // 784*768  = 602112
#define WS_QB    852992      // 784*128  = 100352
#define WS_KVB   953344      // 196*256  = 50176
#define WS_Y     1003520     // 784*256  = 200704
#define WS_GA    1204224     // 784*128  = 100352
// total floats = 1304576 (~5.2 MB)

// ---------- kernel 1: group-mean + 2x2 avg pool + out init ----------
__global__ __launch_bounds__(256) void k_mean_pool(const float* __restrict__ x,
                                                   const float* __restrict__ cls_b,
                                                   float* __restrict__ xm,
                                                   float* __restrict__ xs,
                                                   float* __restrict__ out) {
  const int blk = blockIdx.x;
  const int b = blk / 49;
  const int q = blk % 49;
  const int ph2 = q / 7, pw2 = q % 7;
  const int c = threadIdx.x;
  float s4 = 0.f;
  #pragma unroll
  for (int dy = 0; dy < 2; ++dy) {
    #pragma unroll
    for (int dx = 0; dx < 2; ++dx) {
      const int p = (ph2 * 2 + dy) * 14 + (pw2 * 2 + dx);
      float s = 0.f;
      #pragma unroll
      for (int g = 0; g < 7; ++g)
        s += x[((b * 7 + g) * 196 + p) * 256 + c];
      s *= (1.f / 7.f);
      xm[(b * 196 + p) * 256 + c] = s;
      s4 += s;
    }
  }
  xs[(b * 49 + q) * 256 + c] = s4 * 0.25f;
  if (blk == 0 && c < 8) out[c] = cls_b[c & 1];   // init classifier accumulators
}

// ---------- kernel 2: fused input projections ----------
// region 0 (blocks 0..349): [qkv|q] = xm @ [qkv_w;lq_w]^T  (M=784, N=896, K=256)
// region 1 (blocks 350..377): kv = xs @ lkv_w^T            (M=196, N=256, K=256)
__global__ __launch_bounds__(256) void k_proj_in(const float* __restrict__ xm,
                                                 const float* __restrict__ xs,
                                                 const float* __restrict__ qkv_w,
                                                 const float* __restrict__ lq_w,
                                                 const float* __restrict__ lkv_w,
                                                 float* __restrict__ qkvb,
                                                 float* __restrict__ qb,
                                                 float* __restrict__ kvb) {
  __shared__ float As[32][68];
  __shared__ float Bs[64][68];
  const int tid = threadIdx.x;
  const int tx = tid & 15, ty = tid >> 4;
  const int bid = blockIdx.x;
  int region, mt, nt;
  if (bid < 350) { region = 0; mt = bid / 14; nt = bid % 14; }
  else { const int r = bid - 350; region = 1; mt = r / 4; nt = r % 4; }
  const float* A = region ? xs : xm;
  const int M = region ? 196 : 784;
  const int rowBase = mt * 32;
  const int colBase = nt * 64;

  float acc[2][4] = {{0.f,0.f,0.f,0.f},{0.f,0.f,0.f,0.f}};

  for (int kc = 0; kc < 256; kc += 64) {
    #pragma unroll
    for (int i = 0; i < 2; ++i) {
      const int e = tid + i * 256;
      const int r = e >> 4, k4 = (e & 15) << 2;
      const int row = rowBase + r;
      float4 v = make_float4(0.f, 0.f, 0.f, 0.f);
      if (row < M) v = *(const float4*)(A + (size_t)row * 256 + kc + k4);
      *(float4*)(&As[r][k4]) = v;
    }
    #pragma unroll
    for (int i = 0; i < 4; ++i) {
      const int e = tid + i * 256;
      const int n = e >> 4, k4 = (e & 15) << 2;
      const int col = colBase + n;
      const float* Wp; int wr;
      if (region == 1)      { Wp = lkv_w; wr = col; }
      else if (col < 768)   { Wp = qkv_w; wr = col; }
      else                  { Wp = lq_w;  wr = col - 768; }
      *(float4*)(&Bs[n][k4]) = *(const float4*)(Wp + (size_t)wr * 256 + kc + k4);
    }
    __syncthreads();
    #pragma unroll
    for (int k = 0; k < 64; k += 4) {
      const float4 a0 = *(const float4*)(&As[ty][k]);
      const float4 a1 = *(const float4*)(&As[ty + 16][k]);
      const float4 c0 = *(const float4*)(&Bs[tx][k]);
      const float4 c1 = *(const float4*)(&Bs[tx + 16][k]);
      const float4 c2 = *(const float4*)(&Bs[tx + 32][k]);
      const float4 c3 = *(const float4*)(&Bs[tx + 48][k]);
      acc[0][0] += a0.x*c0.x + a0.y*c0.y + a0.z*c0.z + a0.w*c0.w;
      acc[0][1] += a0.x*c1.x + a0.y*c1.y + a0.z*c1.z + a0.w*c1.w;
      acc[0][2] += a0.x*c2.x + a0.y*c2.y + a0.z*c2.z + a0.w*c2.w;
      acc[0][3] += a0.x*c3.x + a0.y*c3.y + a0.z*c3.z + a0.w*c3.w;
      acc[1][0] += a1.x*c0.x + a1.y*c0.y + a1.z*c0.z + a1.w*c0.w;
      acc[1][1] += a1.x*c1.x + a1.y*c1.y + a1.z*c1.z + a1.w*c1.w;
      acc[1][2] += a1.x*c2.x + a1.y*c2.y + a1.z*c2.z + a1.w*c2.w;
      acc[1][3] += a1.x*c3.x + a1.y*c3.y + a1.z*c3.z + a1.w*c3.w;
    }
    __syncthreads();
  }

  #pragma unroll
  for (int j = 0; j < 4; ++j) {
    const int col = colBase + tx + 16 * j;
    #pragma unroll
    for (int i = 0; i < 2; ++i) {
      const int row = rowBase + ty + 16 * i;
      if (row >= M) continue;
      if (region == 1)    kvb[(size_t)row * 256 + col] = acc[i][j];
      else if (col < 768) qkvb[(size_t)row * 768 + col] = acc[i][j];
      else                qb[(size_t)row * 128 + col - 768] = acc[i][j];
    }
  }
}

// ---------- kernel 3: fused attention (LAE blocks 0..783, GAE blocks 784..799) --
__global__ __launch_bounds__(256) void k_attn(const float* __restrict__ qkvb,
                                              const float* __restrict__ qb,
                                              const float* __restrict__ kvb,
                                              float* __restrict__ y,
                                              float* __restrict__ ga) {
  __shared__ float Ks[49][32];
  __shared__ float Vs[49][32];
  const int bid = blockIdx.x;
  const int tid = threadIdx.x;

  if (bid < 784) {
    // ---- LAE per-pixel dilated 3x3 window attention ----
    const int b = bid / 196, p = bid % 196;
    const int ph = p / 14, pw = p % 14;
    const int c = tid;
    const int d = (c < 128) ? 1 : 3;
    const float qv = qkvb[(size_t)bid * 768 + c];
    float s[9];
    #pragma unroll
    for (int j = 0; j < 9; ++j) {
      const int nh = ph + (j / 3 - 1) * d;
      const int nw = pw + (j % 3 - 1) * d;
      float kval = 0.f;
      if ((unsigned)nh < 14u && (unsigned)nw < 14u)
        kval = qkvb[((size_t)(b * 196 + nh * 14 + nw)) * 768 + 256 + c];
      float t = qv * kval;
      t += __shfl_xor(t, 1);
      t += __shfl_xor(t, 2);
      t += __shfl_xor(t, 4);
      t += __shfl_xor(t, 8);
      t += __shfl_xor(t, 16);
      s[j] = t * 0.17677669529663687f;   // 32^-0.5
    }
    float mx = s[0];
    #pragma unroll
    for (int j = 1; j < 9; ++j) mx = fmaxf(mx, s[j]);
    float sum = 0.f;
    #pragma unroll
    for (int j = 0; j < 9; ++j) { s[j] = __expf(s[j] - mx); sum += s[j]; }
    const float inv = 1.f / sum;
    float o = 0.f;
    #pragma unroll
    for (int j = 0; j < 9; ++j) {
      const int nh = ph + (j / 3 - 1) * d;
      const int nw = pw + (j % 3 - 1) * d;
      if ((unsigned)nh < 14u && (unsigned)nw < 14u)
        o += s[j] * qkvb[((size_t)(b * 196 + nh * 14 + nw)) * 768 + 512 + c];
    }
    y[(size_t)bid * 256 + c] = o * inv;
  } else {
    // ---- GAE attention: 196 queries x 49 keys per (b,head) ----
    const int g = bid - 784;
    const int b = g >> 2, h = g & 3;
    for (int e = tid; e < 49 * 32; e += 256) {
      const int kk = e >> 5, cc = e & 31;
      Ks[kk][cc] = kvb[(size_t)(b * 49 + kk) * 256 + h * 32 + cc];
      Vs[kk][cc] = kvb[(size_t)(b * 49 + kk) * 256 + 128 + h * 32 + cc];
    }
    __syncthreads();
    if (tid < 196) {
      float q[32], o[32];
      #pragma unroll
      for (int cc = 0; cc < 32; ++cc) {
        q[cc] = qb[(size_t)(b * 196 + tid) * 128 + h * 32 + cc];
        o[cc] = 0.f;
      }
      float m = -1e30f, l = 0.f;
      for (int kk = 0; kk < 49; ++kk) {
        float sc = 0.f;
        #pragma unroll
        for (int cc = 0; cc < 32; ++cc) sc += q[cc] * Ks[kk][cc];
        sc *= 0.177f;                  // SCALE_GAE (hard-coded in reference)
        if (sc > m) {
          const float r = __expf(m - sc);
          l *= r;
          #pragma unroll
          for (int cc = 0; cc < 32; ++cc) o[cc] *= r;
          m = sc;
        }
        const float pch = __expf(sc - m);
        l += pch;
        #pragma unroll
        for (int cc = 0; cc < 32; ++cc) o[cc] += pch * Vs[kk][cc];
      }
      const float inv = 1.f / l;
      #pragma unroll
      for (int cc = 0; cc < 32; ++cc)
        ga[(size_t)(b * 196 + tid) * 128 + h * 32 + cc] = o[cc] * inv;
    }
  }
}

// ---------- kernel 4: fused output projections + classifier ----------
// region 0 (112 blocks): lae tile = y_b @ lae_proj_w^T + b  (per-b, 7 ptiles x 4 ntiles)
// region 1 (56 blocks):  gae tile = ga_b @ lproj_w^T + b    (per-b, 7 ptiles x 2 ntiles)
// Each block dots its (bias-added) tile with cls_w rows 0/1 and atomicAdds into out.
__global__ __launch_bounds__(256) void k_proj_cls(const float* __restrict__ y,
                                                  const float* __restrict__ ga,
                                                  const float* __restrict__ lae_w,
                                                  const float* __restrict__ lae_b,
                                                  const float* __restrict__ lproj_w,
                                                  const float* __restrict__ lproj_b,
                                                  const float* __restrict__ cw,
                                                  float* __restrict__ out) {
  __shared__ float As[32][68];
  __shared__ float Bs[64][68];
  const int tid = threadIdx.x;
  const int tx = tid & 15, ty = tid >> 4;
  const int bid = blockIdx.x;
  int region, b, pt, nt;
  if (bid < 112) { region = 0; b = bid / 28; const int r = bid % 28; pt = r / 4; nt = r % 4; }
  else { const int q = bid - 112; region = 1; b = q / 14; const int r = q % 14; pt = r / 2; nt = r % 2; }

  const float* A; const float* W; const float* bias;
  int lda, K, colOff;
  if (region == 0) { A = y  + (size_t)b * 196 * 256; lda = 256; K = 256; W = lae_w;   bias = lae_b;   colOff = 0; }
  else             { A = ga + (size_t)b * 196 * 128; lda = 128; K = 128; W = lproj_w; bias = lproj_b; colOff = 256; }
  const int colBase = nt * 64;

  float acc[2][4] = {{0.f,0.f,0.f,0.f},{0.f,0.f,0.f,0.f}};

  for (int kc = 0; kc < K; kc += 64) {
    #pragma unroll
    for (int i = 0; i < 2; ++i) {
      const int e = tid + i * 256;
      const int r = e >> 4, k4 = (e & 15) << 2;
      const int p = pt * 32 + r;
      float4 v = make_float4(0.f, 0.f, 0.f, 0.f);
      if (p < 196) v = *(const float4*)(A + (size_t)p * lda + kc + k4);
      *(float4*)(&As[r][k4]) = v;
    }
    #pragma unroll
    for (int i = 0; i < 4; ++i) {
      const int e = tid + i * 256;
      const int n = e >> 4, k4 = (e & 15) << 2;
      const int col = colBase + n;
      *(float4*)(&Bs[n][k4]) = *(const float4*)(W + (size_t)col * K + kc + k4);
    }
    __syncthreads();
    #pragma unroll
    for (int k = 0; k < 64; k += 4) {
      const float4 a0 = *(const float4*)(&As[ty][k]);
      const float4 a1 = *(const float4*)(&As[ty + 16][k]);
      const float4 c0 = *(const float4*)(&Bs[tx][k]);
      const float4 c1 = *(const float4*)(&Bs[tx + 16][k]);
      const float4 c2 = *(const float4*)(&Bs[tx + 32][k]);
      const float4 c3 = *(const float4*)(&Bs[tx + 48][k]);
      acc[0][0] += a0.x*c0.x + a0.y*c0.y + a0.z*c0.z + a0.w*c0.w;
      acc[0][1] += a0.x*c1.x + a0.y*c1.y + a0.z*c1.z + a0.w*c1.w;
      acc[0][2] += a0.x*c2.x + a0.y*c2.y + a0.z*c2.z + a0.w*c2.w;
      acc[0][3] += a0.x*c3.x + a0.y*c3.y + a0.z*c3.z + a0.w*c3.w;
      acc[1][0] += a1.x*c0.x + a1.y*c0.y + a1.z*c0.z + a1.w*c0.w;
      acc[1][1] += a1.x*c1.x + a1.y*c1.y + a1.z*c1.z + a1.w*c1.w;
      acc[1][2] += a1.x*c2.x + a1.y*c2.y + a1.z*c2.z + a1.w*c2.w;
      acc[1][3] += a1.x*c3.x + a1.y*c3.y + a1.z*c3.z + a1.w*c3.w;
    }
    __syncthreads();
  }

  // classifier epilogue: s_cls += (acc + bias) * cls_w[cls, p*384 + colOff + col]
  float s0 = 0.f, s1 = 0.f;
  #pragma unroll
  for (int j = 0; j < 4; ++j) {
    const int col = colBase + tx + 16 * j;
    const float bv = bias[col];
    #pragma unroll
    for (int i = 0; i < 2; ++i) {
      const int p = pt * 32 + ty + 16 * i;
      if (p >= 196) continue;
      const float v = acc[i][j] + bv;
      const size_t fidx = (size_t)p * 384 + colOff + col;
      s0 += v * cw[fidx];
      s1 += v * cw[75264 + fidx];
    }
  }
  float* red = &As[0][0];          // reuse LDS (safe: loop ended with syncthreads)
  red[tid] = s0;
  red[256 + tid] = s1;
  __syncthreads();
  for (int st = 128; st > 0; st >>= 1) {
    if (tid < st) { red[tid] += red[tid + st]; red[256 + tid] += red[256 + tid + st]; }
    __syncthreads();
  }
  if (tid == 0) {
    atomicAdd(&out[b * 2 + 0], red[0]);
    atomicAdd(&out[b * 2 + 1], red[256]);
  }
}

extern "C" void kernel_launch(void* const* d_in, const int* in_sizes, int n_in,
                              void* d_out, int out_size, void* d_ws, size_t ws_size,
                              hipStream_t stream) {
  (void)in_sizes; (void)n_in; (void)out_size; (void)ws_size;
  const float* x          = (const float*)d_in[0];
  const float* qkv_w      = (const float*)d_in[1];
  const float* lae_proj_w = (const float*)d_in[2];
  const float* lae_proj_b = (const float*)d_in[3];
  const float* lq_w       = (const float*)d_in[4];
  const float* lkv_w      = (const float*)d_in[5];
  const float* lproj_w    = (const float*)d_in[6];
  const float* lproj_b    = (const float*)d_in[7];
  const float* cls_w      = (const float*)d_in[8];
  const float* cls_b      = (const float*)d_in[9];
  float* out = (float*)d_out;
  float* ws  = (float*)d_ws;

  float* xm   = ws + WS_XM;
  float* xs   = ws + WS_XS;
  float* qkvb = ws + WS_QKV;
  float* qb   = ws + WS_QB;
  float* kvb  = ws + WS_KVB;
  float* y    = ws + WS_Y;
  float* ga   = ws + WS_GA;

  k_mean_pool<<<196, 256, 0, stream>>>(x, cls_b, xm, xs, out);
  k_proj_in<<<378, 256, 0, stream>>>(xm, xs, qkv_w, lq_w, lkv_w, qkvb, qb, kvb);
  k_attn<<<800, 256, 0, stream>>>(qkvb, qb, kvb, y, ga);
  k_proj_cls<<<168, 256, 0, stream>>>(y, ga, lae_proj_w, lae_proj_b,
                                      lproj_w, lproj_b, cls_w, out);
}